// Round 5
// baseline (2187.460 us; speedup 1.0000x reference)
//
#include <hip/hip_runtime.h>

typedef __attribute__((ext_vector_type(8))) _Float16 f16x8;
typedef __attribute__((ext_vector_type(4))) _Float16 f16x4;
typedef __attribute__((ext_vector_type(4))) float f32x4;

// ---------------------------------------------------------------------------
// masks: m = (mask_p < 0.1); x0 = fp16 blocked [b][pix][32] of x*mask
// ---------------------------------------------------------------------------
__global__ void mask_make(const float* __restrict__ x, const float* __restrict__ mp,
                          float* __restrict__ m, _Float16* __restrict__ x0,
                          int B, int HW) {
    int i = blockIdx.x * blockDim.x + threadIdx.x;
    if (i >= B * HW) return;
    float mv = (mp[i] < 0.1f) ? 1.0f : 0.0f;
    m[i] = mv;
    int b = i / HW, p = i - b * HW;
    const float* xb = x + ((size_t)b * 32) * HW + p;
    _Float16* ob = x0 + (size_t)i * 32;
    #pragma unroll
    for (int c = 0; c < 32; ++c) ob[c] = (_Float16)(xb[(size_t)c * HW] * mv);
}

// 3x3 stride-2 pad-1 max-pool on (B,1,H,W) mask
__global__ void mask_down(const float* __restrict__ mi, float* __restrict__ mo,
                          int B, int Hi, int Wi, int Ho, int Wo) {
    int i = blockIdx.x * blockDim.x + threadIdx.x;
    if (i >= B * Ho * Wo) return;
    int wo = i % Wo;
    int t = i / Wo;
    int ho = t % Ho;
    int b = t / Ho;
    float v = 0.0f;
    #pragma unroll
    for (int kh = 0; kh < 3; ++kh) {
        int hi = ho * 2 + kh - 1;
        if (hi < 0 || hi >= Hi) continue;
        #pragma unroll
        for (int kw = 0; kw < 3; ++kw) {
            int wi = wo * 2 + kw - 1;
            if (wi < 0 || wi >= Wi) continue;
            v = fmaxf(v, mi[((size_t)b * Hi + hi) * Wi + wi]);
        }
    }
    mo[i] = v;
}

// active-site compaction (order-independent; each site independent)
__global__ void compact_mask(const float* __restrict__ m, int* __restrict__ act,
                             int* __restrict__ cnt, int HW) {
    int i = blockIdx.x * 256 + threadIdx.x;
    if (i >= 2 * HW) return;
    if (m[i] > 0.5f) {
        int b = i / HW;
        int pos = atomicAdd(&cnt[b], 1);
        act[b * HW + pos] = i - b * HW;
    }
}

// ---------------------------------------------------------------------------
// Fused weight reorder: all 23 tensors, fp32 OIHW -> fp16 [chunk][co][CK],
// chunk = tap*(Cin/CK) + ci/CK, k = ci%CK.
// ---------------------------------------------------------------------------
struct WSeg { const float* src; int cin, cout, ck, cum; };
struct WArgs { WSeg seg[23]; int total; };

__global__ void reorder_all(WArgs A, _Float16* __restrict__ rw) {
    int idx = blockIdx.x * 256 + threadIdx.x;
    if (idx >= A.total) return;
    int s = 0;
    #pragma unroll
    for (int k = 1; k < 23; ++k) if (idx >= A.seg[k].cum) s = k;
    WSeg g = A.seg[s];
    int local = idx - g.cum;
    int kk = local % g.ck;
    int t2 = local / g.ck;
    int co = t2 % g.cout;
    int chunk = t2 / g.cout;
    int chunkc = g.cin / g.ck;
    int tap = chunk / chunkc, cc = chunk - tap * chunkc;
    int ci = cc * g.ck + kk;
    rw[g.cum + local] = (_Float16)g.src[((size_t)co * g.cin + ci) * 9 + tap];
}

// ---------------------------------------------------------------------------
// Dense implicit-GEMM conv3x3 (pad1, stride 1/2), fp16 MFMA, fp32 accum.
// K chunked by CK (32 or 64) tap-major. Acts fp16 blocked [b][ci/32][pix][32].
// ---------------------------------------------------------------------------
template<int BM, int BN, int CK>
__global__ __launch_bounds__(256, 3)
void conv_mfma(const _Float16* __restrict__ in, const _Float16* __restrict__ rw,
               const float* __restrict__ s, const float* __restrict__ t,
               const float* __restrict__ mask, const _Float16* __restrict__ res,
               float* __restrict__ out32, _Float16* __restrict__ out16,
               int Cin, int Cout, int Hin, int Win, int Hout, int Wout,
               int TH, int TW, int stride, int relu)
{
    constexpr int WM = (BM >= 64) ? BM / 2 : BM;
    constexpr int WAVES_M = BM / WM;
    constexpr int WAVES_N = 4 / WAVES_M;
    constexpr int WN = BN / WAVES_N;
    constexpr int MR = WM / 16;
    constexpr int NR = WN / 16;
    constexpr int KH = CK / 32;              // 32-k halves per chunk
    constexpr int ELEMS = (CK * BN) / 256;   // halves staged per thread
    constexpr int NV = ELEMS / 8;
    constexpr int LDST = CK + 8;             // padded row (16B-aligned stride)

    __shared__ _Float16 Bsm[2][BN * LDST];

    const int tid = threadIdx.x;
    const int lane = tid & 63;
    const int wv = tid >> 6;
    const int wm = wv / WAVES_N;
    const int wn = wv % WAVES_N;
    const int row = lane & 15, q = lane >> 4;

    const int tilesX = Wout / TW;
    const int oy0 = (blockIdx.x / tilesX) * TH;
    const int ox0 = (blockIdx.x % tilesX) * TW;
    const int co0 = blockIdx.y * BM;
    const int b = blockIdx.z;

    const int HWin = Hin * Win;
    const int HWo = Hout * Wout;
    const int cicn = Cin >> 5;
    const int cocn = Cout >> 5;
    const int chunkc = Cin / CK;
    const int nIter = 9 * chunkc;

    const int sn = tid & (BN - 1);
    const int kb = (tid / BN) * ELEMS;
    const int sty = sn / TW;
    const int stx = sn - sty * TW;
    const int soy = oy0 + sty;
    const int sox = ox0 + stx;

    f32x4 acc[MR][NR];
    #pragma unroll
    for (int m = 0; m < MR; ++m)
        #pragma unroll
        for (int n = 0; n < NR; ++n)
            #pragma unroll
            for (int r = 0; r < 4; ++r) acc[m][n][r] = 0.0f;

    auto LOADG = [&](int c, f16x8* dst) {
        int tap = c / chunkc, cc = c - tap * chunkc;
        int iy = soy * stride + (tap / 3) - 1;
        int ix = sox * stride + (tap - (tap / 3) * 3) - 1;
        bool ok = (iy >= 0 && iy < Hin && ix >= 0 && ix < Win);
        size_t pixoff = (size_t)iy * Win + ix;
        #pragma unroll
        for (int i = 0; i < NV; ++i) {
            int k = kb + 8 * i;
            const _Float16* p = in +
                (((size_t)(b * cicn + cc * KH + (k >> 5)) * HWin + pixoff) << 5) + (k & 31);
            dst[i] = ok ? *(const f16x8*)p : f16x8{};
        }
    };
    auto WLDS = [&](int buf, const f16x8* v) {
        #pragma unroll
        for (int i = 0; i < NV; ++i)
            *(f16x8*)&Bsm[buf][sn * LDST + kb + 8 * i] = v[i];
    };

    f16x8 v[NV];
    LOADG(0, v);
    WLDS(0, v);
    __syncthreads();

    for (int c = 0; c < nIter; ++c) {
        f16x8 v2[NV];
        if (c + 1 < nIter) LOADG(c + 1, v2);

        f16x8 ah[KH][MR], bh[KH][NR];
        #pragma unroll
        for (int m = 0; m < MR; ++m) {
            int co = co0 + wm * WM + m * 16 + row;
            const _Float16* ap = rw + ((size_t)c * Cout + co) * CK + (q << 3);
            #pragma unroll
            for (int h = 0; h < KH; ++h) ah[h][m] = *(const f16x8*)(ap + 32 * h);
        }
        const _Float16* bp = &Bsm[c & 1][0];
        #pragma unroll
        for (int n = 0; n < NR; ++n) {
            int nl = wn * WN + n * 16 + row;
            const _Float16* bb = bp + nl * LDST + (q << 3);
            #pragma unroll
            for (int h = 0; h < KH; ++h) bh[h][n] = *(const f16x8*)(bb + 32 * h);
        }
        #pragma unroll
        for (int h = 0; h < KH; ++h)
            #pragma unroll
            for (int m = 0; m < MR; ++m)
                #pragma unroll
                for (int n = 0; n < NR; ++n)
                    acc[m][n] = __builtin_amdgcn_mfma_f32_16x16x32_f16(ah[h][m], bh[h][n], acc[m][n], 0, 0, 0);

        if (c + 1 < nIter) WLDS((c + 1) & 1, v2);
        __syncthreads();
    }

    int pix[NR]; float mv[NR];
    #pragma unroll
    for (int n = 0; n < NR; ++n) {
        int nl = wn * WN + n * 16 + row;
        int ty = nl / TW, tx = nl - ty * TW;
        pix[n] = (oy0 + ty) * Wout + (ox0 + tx);
        mv[n] = mask ? mask[(size_t)b * HWo + pix[n]] : 1.0f;
    }
    #pragma unroll
    for (int m = 0; m < MR; ++m) {
        int cb = co0 + wm * WM + m * 16 + q * 4;
        float sc[4], sh[4];
        #pragma unroll
        for (int r = 0; r < 4; ++r) { sc[r] = s[cb + r]; sh[r] = t[cb + r]; }
        #pragma unroll
        for (int n = 0; n < NR; ++n) {
            size_t boff = ((size_t)(b * cocn + (cb >> 5)) * HWo + pix[n]) * 32 + (cb & 31);
            float val[4];
            #pragma unroll
            for (int r = 0; r < 4; ++r) val[r] = (acc[m][n][r] * sc[r] + sh[r]) * mv[n];
            if (res) {
                f16x4 rv = *(const f16x4*)&res[boff];
                #pragma unroll
                for (int r = 0; r < 4; ++r) val[r] += (float)rv[r];
            }
            if (relu) {
                #pragma unroll
                for (int r = 0; r < 4; ++r) val[r] = fmaxf(val[r], 0.0f);
            }
            if (out16) {
                f16x4 pk;
                #pragma unroll
                for (int r = 0; r < 4; ++r) pk[r] = (_Float16)val[r];
                *(f16x4*)&out16[boff] = pk;
            }
            if (out32) {
                #pragma unroll
                for (int r = 0; r < 4; ++r)
                    out32[((size_t)b * Cout + cb + r) * HWo + pix[n]] = val[r];
            }
        }
    }
}

// ---------------------------------------------------------------------------
// Sparse stage-1 conv: Cin=Cout=32, gathered over active-site list.
// Output written ONLY at active sites (buffers pre-zeroed at inactive sites).
// ---------------------------------------------------------------------------
__global__ __launch_bounds__(256, 3)
void conv_sparse(const _Float16* __restrict__ in, const _Float16* __restrict__ rw,
                 const float* __restrict__ s, const float* __restrict__ t,
                 const int* __restrict__ act, const int* __restrict__ cnt,
                 const _Float16* __restrict__ res,
                 float* __restrict__ out32, _Float16* __restrict__ out16,
                 int Hin, int Win, int relu)
{
    constexpr int BN = 256;
    constexpr int LDST = 40;
    constexpr int MR = 2, NR = 4;   // BM=32: 1x4 waves, WN=64
    __shared__ _Float16 Bsm[2][BN * LDST];

    const int tid = threadIdx.x;
    const int lane = tid & 63;
    const int wv = tid >> 6;
    const int row = lane & 15, q = lane >> 4;
    const int b = blockIdx.z;
    const int HW = Hin * Win;
    const int nb = cnt[b];
    const int n0 = blockIdx.x * BN;
    if (n0 >= nb) return;

    const int jt = n0 + tid;
    const bool vt = jt < nb;
    const int p = vt ? act[b * HW + jt] : 0;
    const int py = p / Win, px = p - py * Win;
    const _Float16* inb = in + ((size_t)b * HW << 5);

    f32x4 acc[MR][NR];
    #pragma unroll
    for (int m = 0; m < MR; ++m)
        #pragma unroll
        for (int n = 0; n < NR; ++n)
            #pragma unroll
            for (int r = 0; r < 4; ++r) acc[m][n][r] = 0.0f;

    auto LOADG = [&](int c, f16x8* dst) {
        int dy = c / 3 - 1, dx = c - (c / 3) * 3 - 1;
        int iy = py + dy, ix = px + dx;
        bool ok = vt && iy >= 0 && iy < Hin && ix >= 0 && ix < Win;
        const _Float16* pp = inb + ((size_t)(iy * Win + ix) << 5);
        #pragma unroll
        for (int i = 0; i < 4; ++i) dst[i] = ok ? *(const f16x8*)(pp + 8 * i) : f16x8{};
    };
    auto WLDS = [&](int buf, const f16x8* v) {
        #pragma unroll
        for (int i = 0; i < 4; ++i)
            *(f16x8*)&Bsm[buf][tid * LDST + 8 * i] = v[i];
    };

    f16x8 v[4];
    LOADG(0, v);
    WLDS(0, v);
    __syncthreads();

    for (int c = 0; c < 9; ++c) {
        f16x8 v2[4];
        if (c < 8) LOADG(c + 1, v2);

        f16x8 ah[MR], bh[NR];
        #pragma unroll
        for (int m = 0; m < MR; ++m) {
            int co = m * 16 + row;
            ah[m] = *(const f16x8*)(rw + ((size_t)c * 32 + co) * 32 + (q << 3));
        }
        const _Float16* bp = &Bsm[c & 1][0];
        #pragma unroll
        for (int n = 0; n < NR; ++n) {
            int nl = wv * 64 + n * 16 + row;
            bh[n] = *(const f16x8*)(bp + nl * LDST + (q << 3));
        }
        #pragma unroll
        for (int m = 0; m < MR; ++m)
            #pragma unroll
            for (int n = 0; n < NR; ++n)
                acc[m][n] = __builtin_amdgcn_mfma_f32_16x16x32_f16(ah[m], bh[n], acc[m][n], 0, 0, 0);

        if (c < 8) WLDS((c + 1) & 1, v2);
        __syncthreads();
    }

    #pragma unroll
    for (int n = 0; n < NR; ++n) {
        int jn = n0 + wv * 64 + n * 16 + row;
        bool vn = jn < nb;
        int pn = vn ? act[b * HW + jn] : 0;
        size_t pbase = ((size_t)b * HW + pn) << 5;
        #pragma unroll
        for (int m = 0; m < MR; ++m) {
            int cb = m * 16 + q * 4;
            float val[4];
            #pragma unroll
            for (int r = 0; r < 4; ++r) val[r] = acc[m][n][r] * s[cb + r] + t[cb + r];
            if (res && vn) {
                f16x4 rv = *(const f16x4*)&res[pbase + cb];
                #pragma unroll
                for (int r = 0; r < 4; ++r) val[r] += (float)rv[r];
            }
            if (relu) {
                #pragma unroll
                for (int r = 0; r < 4; ++r) val[r] = fmaxf(val[r], 0.0f);
            }
            if (vn) {
                f16x4 pk;
                #pragma unroll
                for (int r = 0; r < 4; ++r) pk[r] = (_Float16)val[r];
                *(f16x4*)&out16[pbase + cb] = pk;
                if (out32) {
                    #pragma unroll
                    for (int r = 0; r < 4; ++r)
                        out32[((size_t)(b * 32 + cb + r)) * HW + pn] = val[r];
                }
            }
        }
    }
}

extern "C" void kernel_launch(void* const* d_in, const int* in_sizes, int n_in,
                              void* d_out, int out_size, void* d_ws, size_t ws_size,
                              hipStream_t stream) {
    const int B = 2;

    const float* x      = (const float*)d_in[0];
    const float* mask_p = (const float*)d_in[1];
    const float* w1  = (const float*)d_in[2];
    const float* s1  = (const float*)d_in[3];
    const float* t1  = (const float*)d_in[4];
    const float* wd2 = (const float*)d_in[5];
    const float* w2  = (const float*)d_in[6];
    const float* s2  = (const float*)d_in[7];
    const float* t2  = (const float*)d_in[8];
    const float* wd3 = (const float*)d_in[9];
    const float* w3  = (const float*)d_in[10];
    const float* s3  = (const float*)d_in[11];
    const float* t3  = (const float*)d_in[12];
    const float* wd4 = (const float*)d_in[13];
    const float* w4  = (const float*)d_in[14];
    const float* s4  = (const float*)d_in[15];
    const float* t4  = (const float*)d_in[16];
    const float* w5  = (const float*)d_in[17];
    const float* s5  = (const float*)d_in[18];
    const float* t5  = (const float*)d_in[19];

    // d_out slices (fp32 NCHW)
    float* x1o = (float*)d_out;
    float* x2o = x1o + 16777216;
    float* x3o = x2o + 8388608;
    float* x4o = x3o + 4194304;
    float* x5o = x4o + 2097152;

    // workspace
    _Float16* rwbase = (_Float16*)d_ws;        // 5,299,200 halves
    float* m1 = (float*)d_ws + 2649600;
    float* m2 = m1 + 524288;
    float* m3 = m2 + 131072;
    float* m4 = m3 + 32768;
    int* act  = (int*)(m4 + 8192);             // 524288 ints
    int* cnt  = act + 524288;                  // 2 ints (+pad)
    _Float16* P = (_Float16*)(cnt + 32);
    _Float16* Q = P + 16777216;
    _Float16* R = Q + 16777216;

    // ---- fused weight reorder (1 launch) ----
    WArgs wa;
    int cum = 0, si = 0;
    const _Float16* rp[23];
    auto addseg = [&](const float* src, int cin, int cout, int ck) {
        wa.seg[si].src = src; wa.seg[si].cin = cin; wa.seg[si].cout = cout;
        wa.seg[si].ck = ck; wa.seg[si].cum = cum;
        rp[si] = rwbase + cum;
        cum += cout * cin * 9; si++;
    };
    for (int i = 0; i < 5; ++i) addseg(w1 + (size_t)i * 9216, 32, 32, 32);
    addseg(wd2, 32, 64, 32);
    for (int i = 0; i < 4; ++i) addseg(w2 + (size_t)i * 36864, 64, 64, 64);
    addseg(wd3, 64, 128, 64);
    for (int i = 0; i < 4; ++i) addseg(w3 + (size_t)i * 147456, 128, 128, 64);
    addseg(wd4, 128, 256, 64);
    for (int i = 0; i < 4; ++i) addseg(w4 + (size_t)i * 589824, 256, 256, 64);
    for (int i = 0; i < 3; ++i) addseg(w5 + (size_t)i * 589824, 256, 256, 64);
    wa.total = cum;  // 5,299,200
    reorder_all<<<(cum + 255) / 256, 256, 0, stream>>>(wa, rwbase);

    // ---- zero-init sparse-written buffers + counters ----
    hipMemsetAsync(cnt, 0, 2 * sizeof(int), stream);
    hipMemsetAsync(Q, 0, 16777216 * sizeof(_Float16), stream);
    hipMemsetAsync(R, 0, 16777216 * sizeof(_Float16), stream);
    hipMemsetAsync(x1o, 0, 16777216 * sizeof(float), stream);

    // ---- masks + x0 + compaction ----
    {
        int n = B * 512 * 512;
        mask_make<<<(n + 255) / 256, 256, 0, stream>>>(x, mask_p, m1, P, B, 512 * 512);
        mask_down<<<(B * 256 * 256 + 255) / 256, 256, 0, stream>>>(m1, m2, B, 512, 512, 256, 256);
        mask_down<<<(B * 128 * 128 + 255) / 256, 256, 0, stream>>>(m2, m3, B, 256, 256, 128, 128);
        mask_down<<<(B * 64 * 64 + 255) / 256, 256, 0, stream>>>(m3, m4, B, 128, 128, 64, 64);
        compact_mask<<<(n + 255) / 256, 256, 0, stream>>>(m1, act, cnt, 512 * 512);
    }

    auto conv = [&](const _Float16* in, const _Float16* rwp, const float* sp, const float* tp,
                    const float* mk, const _Float16* rs, float* o32, _Float16* o16,
                    int Cin, int Cout, int Hin, int Win, int stride, int BM, int BN, int CK) {
        int Hout = Hin / stride, Wout = Win / stride, HWo = Hout * Wout;
        int TW = (Wout < BN) ? Wout : BN;
        int TH = BN / TW;
        dim3 grid(HWo / BN, Cout / BM, B);
        if (BM == 64 && BN == 128 && CK == 32)
            conv_mfma<64, 128, 32><<<grid, 256, 0, stream>>>(in, rwp, sp, tp, mk, rs, o32, o16,
                Cin, Cout, Hin, Win, Hout, Wout, TH, TW, stride, 1);
        else if (BM == 64 && BN == 128 && CK == 64)
            conv_mfma<64, 128, 64><<<grid, 256, 0, stream>>>(in, rwp, sp, tp, mk, rs, o32, o16,
                Cin, Cout, Hin, Win, Hout, Wout, TH, TW, stride, 1);
        else
            conv_mfma<128, 64, 64><<<grid, 256, 0, stream>>>(in, rwp, sp, tp, mk, rs, o32, o16,
                Cin, Cout, Hin, Win, Hout, Wout, TH, TW, stride, 1);
    };
    auto sconv = [&](const _Float16* in, const _Float16* rwp, const float* sp, const float* tp,
                     const _Float16* rs, float* o32, _Float16* o16) {
        dim3 grid(1024, 1, B);
        conv_sparse<<<grid, 256, 0, stream>>>(in, rwp, sp, tp, act, cnt, rs, o32, o16, 512, 512, 1);
    };

    // ---- stage 1 (32ch, 512x512) sparse: P=x0 ----
    sconv(P, rp[0], s1 + 0,   t1 + 0,   nullptr, nullptr, Q);
    sconv(Q, rp[1], s1 + 32,  t1 + 32,  nullptr, nullptr, R);
    sconv(R, rp[2], s1 + 64,  t1 + 64,  Q,       nullptr, P);   // P inactive sites = 0 from x0
    sconv(P, rp[3], s1 + 96,  t1 + 96,  nullptr, nullptr, Q);
    sconv(Q, rp[4], s1 + 128, t1 + 128, P,       x1o,     R);   // x1 = R

    // ---- stage 2 (32->64, 512->256): in R ----
    conv(R, rp[5], s2 + 0,   t2 + 0,   m2, nullptr, nullptr, P, 32, 64, 512, 512, 2, 64, 128, 32);
    conv(P, rp[6], s2 + 64,  t2 + 64,  m2, nullptr, nullptr, Q, 64, 64, 256, 256, 1, 64, 128, 64);
    conv(Q, rp[7], s2 + 128, t2 + 128, m2, P,       nullptr, P, 64, 64, 256, 256, 1, 64, 128, 64);
    conv(P, rp[8], s2 + 192, t2 + 192, m2, nullptr, nullptr, Q, 64, 64, 256, 256, 1, 64, 128, 64);
    conv(Q, rp[9], s2 + 256, t2 + 256, m2, P,       x2o,     P, 64, 64, 256, 256, 1, 64, 128, 64);

    // ---- stage 3 (64->128, 256->128): x2 = P ----
    conv(P, rp[10], s3 + 0,   t3 + 0,   m3, nullptr, nullptr, Q, 64, 128, 256, 256, 2, 128, 64, 64);
    conv(Q, rp[11], s3 + 128, t3 + 128, m3, nullptr, nullptr, R, 128, 128, 128, 128, 1, 128, 64, 64);
    conv(R, rp[12], s3 + 256, t3 + 256, m3, Q,       nullptr, Q, 128, 128, 128, 128, 1, 128, 64, 64);
    conv(Q, rp[13], s3 + 384, t3 + 384, m3, nullptr, nullptr, R, 128, 128, 128, 128, 1, 128, 64, 64);
    conv(R, rp[14], s3 + 512, t3 + 512, m3, Q,       x3o,     Q, 128, 128, 128, 128, 1, 128, 64, 64);

    // ---- stage 4 (128->256, 128->64): x3 = Q ----
    conv(Q, rp[15], s4 + 0,    t4 + 0,    m4, nullptr, nullptr, P, 128, 256, 128, 128, 2, 128, 64, 64);
    conv(P, rp[16], s4 + 256,  t4 + 256,  m4, nullptr, nullptr, R, 256, 256, 64, 64, 1, 128, 64, 64);
    conv(R, rp[17], s4 + 512,  t4 + 512,  m4, P,       nullptr, P, 256, 256, 64, 64, 1, 128, 64, 64);
    conv(P, rp[18], s4 + 768,  t4 + 768,  m4, nullptr, nullptr, R, 256, 256, 64, 64, 1, 128, 64, 64);
    conv(R, rp[19], s4 + 1024, t4 + 1024, m4, P,       x4o,     P, 256, 256, 64, 64, 1, 128, 64, 64);

    // ---- conv5 (dense): x4 = P ----
    conv(P, rp[20], s5 + 0,   t5 + 0,   nullptr, nullptr, nullptr, Q, 256, 256, 64, 64, 2, 128, 64, 64);
    conv(Q, rp[21], s5 + 256, t5 + 256, nullptr, nullptr, nullptr, R, 256, 256, 32, 32, 1, 128, 64, 64);
    conv(R, rp[22], s5 + 512, t5 + 512, nullptr, nullptr, x5o, nullptr, 256, 256, 32, 32, 1, 128, 64, 64);
}

// Round 6
// 1557.701 us; speedup vs baseline: 1.4043x; 1.4043x over previous
//
#include <hip/hip_runtime.h>

typedef __attribute__((ext_vector_type(8))) _Float16 f16x8;
typedef __attribute__((ext_vector_type(4))) _Float16 f16x4;
typedef __attribute__((ext_vector_type(4))) float f32x4;

// ---------------------------------------------------------------------------
// mask_make: m = (mask_p < 0.1); x0 = fp16 blocked [b][pix][32] of x*mask;
// fused block-aggregated active-site compaction (1 global atomic / block).
// ---------------------------------------------------------------------------
__global__ void mask_make(const float* __restrict__ x, const float* __restrict__ mp,
                          float* __restrict__ m, _Float16* __restrict__ x0,
                          int* __restrict__ act, int* __restrict__ cnt,
                          int B, int HW) {
    int i = blockIdx.x * blockDim.x + threadIdx.x;
    const int tid = threadIdx.x;
    const int lane = tid & 63;
    const int wv = tid >> 6;
    if (i >= B * HW) return;                  // exact grid; uniform anyway
    bool active = (mp[i] < 0.1f);
    float mv = active ? 1.0f : 0.0f;
    m[i] = mv;
    int b = i / HW, p = i - b * HW;           // b uniform per block (HW % 256 == 0)
    const float* xb = x + ((size_t)b * 32) * HW + p;
    _Float16* ob = x0 + (size_t)i * 32;
    #pragma unroll
    for (int c = 0; c < 32; ++c) ob[c] = (_Float16)(xb[(size_t)c * HW] * mv);

    // ---- compaction ----
    __shared__ int wcnt[4];
    __shared__ int bbase;
    unsigned long long ball = __ballot(active);
    int wtot = __popcll(ball);
    int prefix = __popcll(ball & ((1ull << lane) - 1ull));
    if (lane == 0) wcnt[wv] = wtot;
    __syncthreads();
    if (tid == 0) {
        int s = 0;
        #pragma unroll
        for (int w = 0; w < 4; ++w) { int tv = wcnt[w]; wcnt[w] = s; s += tv; }
        bbase = (s > 0) ? atomicAdd(&cnt[b], s) : 0;
    }
    __syncthreads();
    if (active) act[b * HW + bbase + wcnt[wv] + prefix] = p;
}

// 3x3 stride-2 pad-1 max-pool on (B,1,H,W) mask
__global__ void mask_down(const float* __restrict__ mi, float* __restrict__ mo,
                          int B, int Hi, int Wi, int Ho, int Wo) {
    int i = blockIdx.x * blockDim.x + threadIdx.x;
    if (i >= B * Ho * Wo) return;
    int wo = i % Wo;
    int t = i / Wo;
    int ho = t % Ho;
    int b = t / Ho;
    float v = 0.0f;
    #pragma unroll
    for (int kh = 0; kh < 3; ++kh) {
        int hi = ho * 2 + kh - 1;
        if (hi < 0 || hi >= Hi) continue;
        #pragma unroll
        for (int kw = 0; kw < 3; ++kw) {
            int wi = wo * 2 + kw - 1;
            if (wi < 0 || wi >= Wi) continue;
            v = fmaxf(v, mi[((size_t)b * Hi + hi) * Wi + wi]);
        }
    }
    mo[i] = v;
}

// ---------------------------------------------------------------------------
// Fused weight reorder: all 23 tensors, fp32 OIHW -> fp16 [chunk][co][CK]
// ---------------------------------------------------------------------------
struct WSeg { const float* src; int cin, cout, ck, cum; };
struct WArgs { WSeg seg[23]; int total; };

__global__ void reorder_all(WArgs A, _Float16* __restrict__ rw) {
    int idx = blockIdx.x * 256 + threadIdx.x;
    if (idx >= A.total) return;
    int s = 0;
    #pragma unroll
    for (int k = 1; k < 23; ++k) if (idx >= A.seg[k].cum) s = k;
    WSeg g = A.seg[s];
    int local = idx - g.cum;
    int kk = local % g.ck;
    int t2 = local / g.ck;
    int co = t2 % g.cout;
    int chunk = t2 / g.cout;
    int chunkc = g.cin / g.ck;
    int tap = chunk / chunkc, cc = chunk - tap * chunkc;
    int ci = cc * g.ck + kk;
    rw[g.cum + local] = (_Float16)g.src[((size_t)co * g.cin + ci) * 9 + tap];
}

// ---------------------------------------------------------------------------
// Dense implicit-GEMM conv3x3 (pad1, stride 1/2), fp16 MFMA, fp32 accum.
// ---------------------------------------------------------------------------
template<int BM, int BN, int CK>
__global__ __launch_bounds__(256, 3)
void conv_mfma(const _Float16* __restrict__ in, const _Float16* __restrict__ rw,
               const float* __restrict__ s, const float* __restrict__ t,
               const float* __restrict__ mask, const _Float16* __restrict__ res,
               float* __restrict__ out32, _Float16* __restrict__ out16,
               int Cin, int Cout, int Hin, int Win, int Hout, int Wout,
               int TH, int TW, int stride, int relu)
{
    constexpr int WM = (BM >= 64) ? BM / 2 : BM;
    constexpr int WAVES_M = BM / WM;
    constexpr int WAVES_N = 4 / WAVES_M;
    constexpr int WN = BN / WAVES_N;
    constexpr int MR = WM / 16;
    constexpr int NR = WN / 16;
    constexpr int KH = CK / 32;
    constexpr int ELEMS = (CK * BN) / 256;
    constexpr int NV = ELEMS / 8;
    constexpr int LDST = CK + 8;

    __shared__ _Float16 Bsm[2][BN * LDST];

    const int tid = threadIdx.x;
    const int lane = tid & 63;
    const int wv = tid >> 6;
    const int wm = wv / WAVES_N;
    const int wn = wv % WAVES_N;
    const int row = lane & 15, q = lane >> 4;

    const int tilesX = Wout / TW;
    const int oy0 = (blockIdx.x / tilesX) * TH;
    const int ox0 = (blockIdx.x % tilesX) * TW;
    const int co0 = blockIdx.y * BM;
    const int b = blockIdx.z;

    const int HWin = Hin * Win;
    const int HWo = Hout * Wout;
    const int cicn = Cin >> 5;
    const int cocn = Cout >> 5;
    const int chunkc = Cin / CK;
    const int nIter = 9 * chunkc;

    const int sn = tid & (BN - 1);
    const int kb = (tid / BN) * ELEMS;
    const int sty = sn / TW;
    const int stx = sn - sty * TW;
    const int soy = oy0 + sty;
    const int sox = ox0 + stx;

    f32x4 acc[MR][NR];
    #pragma unroll
    for (int m = 0; m < MR; ++m)
        #pragma unroll
        for (int n = 0; n < NR; ++n)
            #pragma unroll
            for (int r = 0; r < 4; ++r) acc[m][n][r] = 0.0f;

    auto LOADG = [&](int c, f16x8* dst) {
        int tap = c / chunkc, cc = c - tap * chunkc;
        int iy = soy * stride + (tap / 3) - 1;
        int ix = sox * stride + (tap - (tap / 3) * 3) - 1;
        bool ok = (iy >= 0 && iy < Hin && ix >= 0 && ix < Win);
        size_t pixoff = (size_t)iy * Win + ix;
        #pragma unroll
        for (int i = 0; i < NV; ++i) {
            int k = kb + 8 * i;
            const _Float16* p = in +
                (((size_t)(b * cicn + cc * KH + (k >> 5)) * HWin + pixoff) << 5) + (k & 31);
            dst[i] = ok ? *(const f16x8*)p : f16x8{};
        }
    };
    auto WLDS = [&](int buf, const f16x8* v) {
        #pragma unroll
        for (int i = 0; i < NV; ++i)
            *(f16x8*)&Bsm[buf][sn * LDST + kb + 8 * i] = v[i];
    };

    f16x8 v[NV];
    LOADG(0, v);
    WLDS(0, v);
    __syncthreads();

    for (int c = 0; c < nIter; ++c) {
        f16x8 v2[NV];
        if (c + 1 < nIter) LOADG(c + 1, v2);

        f16x8 ah[KH][MR], bh[KH][NR];
        #pragma unroll
        for (int m = 0; m < MR; ++m) {
            int co = co0 + wm * WM + m * 16 + row;
            const _Float16* ap = rw + ((size_t)c * Cout + co) * CK + (q << 3);
            #pragma unroll
            for (int h = 0; h < KH; ++h) ah[h][m] = *(const f16x8*)(ap + 32 * h);
        }
        const _Float16* bp = &Bsm[c & 1][0];
        #pragma unroll
        for (int n = 0; n < NR; ++n) {
            int nl = wn * WN + n * 16 + row;
            const _Float16* bb = bp + nl * LDST + (q << 3);
            #pragma unroll
            for (int h = 0; h < KH; ++h) bh[h][n] = *(const f16x8*)(bb + 32 * h);
        }
        #pragma unroll
        for (int h = 0; h < KH; ++h)
            #pragma unroll
            for (int m = 0; m < MR; ++m)
                #pragma unroll
                for (int n = 0; n < NR; ++n)
                    acc[m][n] = __builtin_amdgcn_mfma_f32_16x16x32_f16(ah[h][m], bh[h][n], acc[m][n], 0, 0, 0);

        if (c + 1 < nIter) WLDS((c + 1) & 1, v2);
        __syncthreads();
    }

    int pix[NR]; float mv[NR];
    #pragma unroll
    for (int n = 0; n < NR; ++n) {
        int nl = wn * WN + n * 16 + row;
        int ty = nl / TW, tx = nl - ty * TW;
        pix[n] = (oy0 + ty) * Wout + (ox0 + tx);
        mv[n] = mask ? mask[(size_t)b * HWo + pix[n]] : 1.0f;
    }
    #pragma unroll
    for (int m = 0; m < MR; ++m) {
        int cb = co0 + wm * WM + m * 16 + q * 4;
        float sc[4], sh[4];
        #pragma unroll
        for (int r = 0; r < 4; ++r) { sc[r] = s[cb + r]; sh[r] = t[cb + r]; }
        #pragma unroll
        for (int n = 0; n < NR; ++n) {
            size_t boff = ((size_t)(b * cocn + (cb >> 5)) * HWo + pix[n]) * 32 + (cb & 31);
            float val[4];
            #pragma unroll
            for (int r = 0; r < 4; ++r) val[r] = (acc[m][n][r] * sc[r] + sh[r]) * mv[n];
            if (res) {
                f16x4 rv = *(const f16x4*)&res[boff];
                #pragma unroll
                for (int r = 0; r < 4; ++r) val[r] += (float)rv[r];
            }
            if (relu) {
                #pragma unroll
                for (int r = 0; r < 4; ++r) val[r] = fmaxf(val[r], 0.0f);
            }
            if (out16) {
                f16x4 pk;
                #pragma unroll
                for (int r = 0; r < 4; ++r) pk[r] = (_Float16)val[r];
                *(f16x4*)&out16[boff] = pk;
            }
            if (out32) {
                #pragma unroll
                for (int r = 0; r < 4; ++r)
                    out32[((size_t)b * Cout + cb + r) * HWo + pix[n]] = val[r];
            }
        }
    }
}

// ---------------------------------------------------------------------------
// Sparse stage-1 conv, barrier-free: Cin=Cout=32 gathered over active list.
// Each wave owns 32 sites (2 n-tiles of 16). Lane (row,q) global-loads its
// MFMA B-fragment directly: 16B slice of neighbor pixel's 64B channel block.
// No LDS, no __syncthreads -> latency hidden by independent waves.
// ---------------------------------------------------------------------------
__global__ __launch_bounds__(256, 4)
void conv_sparse(const _Float16* __restrict__ in, const _Float16* __restrict__ rw,
                 const float* __restrict__ s, const float* __restrict__ t,
                 const int* __restrict__ act, const int* __restrict__ cnt,
                 const _Float16* __restrict__ res,
                 float* __restrict__ out32, _Float16* __restrict__ out16,
                 int Hin, int Win, int relu)
{
    constexpr int NR = 2;                 // 16-pixel tiles per wave
    const int tid = threadIdx.x;
    const int lane = tid & 63;
    const int wv = tid >> 6;
    const int row = lane & 15, q = lane >> 4;
    const int b = blockIdx.z;
    const int HW = Hin * Win;
    const int nb = cnt[b];
    const int base = (blockIdx.x * 4 + wv) * (16 * NR);
    if (base >= nb) return;

    const int* actb = act + b * HW;
    const _Float16* inb = in + ((size_t)b * HW << 5);

    int pn[NR], py[NR], px[NR]; bool vn[NR];
    #pragma unroll
    for (int n = 0; n < NR; ++n) {
        int j = base + n * 16 + row;
        vn[n] = j < nb;
        pn[n] = vn[n] ? actb[j] : 0;
        py[n] = pn[n] / Win;
        px[n] = pn[n] - py[n] * Win;
    }

    f32x4 acc[2][NR];
    #pragma unroll
    for (int m = 0; m < 2; ++m)
        #pragma unroll
        for (int n = 0; n < NR; ++n)
            #pragma unroll
            for (int r = 0; r < 4; ++r) acc[m][n][r] = 0.0f;

    #pragma unroll
    for (int c = 0; c < 9; ++c) {
        const int dy = c / 3 - 1, dx = c - (c / 3) * 3 - 1;
        f16x8 a0 = *(const f16x8*)(rw + ((size_t)c * 32 + row) * 32 + (q << 3));
        f16x8 a1 = *(const f16x8*)(rw + ((size_t)c * 32 + 16 + row) * 32 + (q << 3));
        #pragma unroll
        for (int n = 0; n < NR; ++n) {
            int iy = py[n] + dy, ix = px[n] + dx;
            bool ok = vn[n] && iy >= 0 && iy < Hin && ix >= 0 && ix < Win;
            f16x8 bf = ok ? *(const f16x8*)(inb + ((size_t)(iy * Win + ix) << 5) + (q << 3))
                          : f16x8{};
            acc[0][n] = __builtin_amdgcn_mfma_f32_16x16x32_f16(a0, bf, acc[0][n], 0, 0, 0);
            acc[1][n] = __builtin_amdgcn_mfma_f32_16x16x32_f16(a1, bf, acc[1][n], 0, 0, 0);
        }
    }

    #pragma unroll
    for (int n = 0; n < NR; ++n) {
        if (!vn[n]) continue;
        size_t pbase = ((size_t)b * HW + pn[n]) << 5;
        #pragma unroll
        for (int m = 0; m < 2; ++m) {
            int cb = m * 16 + q * 4;
            float val[4];
            #pragma unroll
            for (int r = 0; r < 4; ++r) val[r] = acc[m][n][r] * s[cb + r] + t[cb + r];
            if (res) {
                f16x4 rv = *(const f16x4*)&res[pbase + cb];
                #pragma unroll
                for (int r = 0; r < 4; ++r) val[r] += (float)rv[r];
            }
            if (relu) {
                #pragma unroll
                for (int r = 0; r < 4; ++r) val[r] = fmaxf(val[r], 0.0f);
            }
            f16x4 pk;
            #pragma unroll
            for (int r = 0; r < 4; ++r) pk[r] = (_Float16)val[r];
            *(f16x4*)&out16[pbase + cb] = pk;
            if (out32) {
                #pragma unroll
                for (int r = 0; r < 4; ++r)
                    out32[((size_t)(b * 32 + cb + r)) * HW + pn[n]] = val[r];
            }
        }
    }
}

extern "C" void kernel_launch(void* const* d_in, const int* in_sizes, int n_in,
                              void* d_out, int out_size, void* d_ws, size_t ws_size,
                              hipStream_t stream) {
    const int B = 2;

    const float* x      = (const float*)d_in[0];
    const float* mask_p = (const float*)d_in[1];
    const float* w1  = (const float*)d_in[2];
    const float* s1  = (const float*)d_in[3];
    const float* t1  = (const float*)d_in[4];
    const float* wd2 = (const float*)d_in[5];
    const float* w2  = (const float*)d_in[6];
    const float* s2  = (const float*)d_in[7];
    const float* t2  = (const float*)d_in[8];
    const float* wd3 = (const float*)d_in[9];
    const float* w3  = (const float*)d_in[10];
    const float* s3  = (const float*)d_in[11];
    const float* t3  = (const float*)d_in[12];
    const float* wd4 = (const float*)d_in[13];
    const float* w4  = (const float*)d_in[14];
    const float* s4  = (const float*)d_in[15];
    const float* t4  = (const float*)d_in[16];
    const float* w5  = (const float*)d_in[17];
    const float* s5  = (const float*)d_in[18];
    const float* t5  = (const float*)d_in[19];

    // d_out slices (fp32 NCHW)
    float* x1o = (float*)d_out;
    float* x2o = x1o + 16777216;
    float* x3o = x2o + 8388608;
    float* x4o = x3o + 4194304;
    float* x5o = x4o + 2097152;

    // workspace
    _Float16* rwbase = (_Float16*)d_ws;        // 5,299,200 halves
    float* m1 = (float*)d_ws + 2649600;
    float* m2 = m1 + 524288;
    float* m3 = m2 + 131072;
    float* m4 = m3 + 32768;
    int* act  = (int*)(m4 + 8192);             // 524288 ints
    int* cnt  = act + 524288;                  // 2 ints (+pad)
    _Float16* P = (_Float16*)(cnt + 32);
    _Float16* Q = P + 16777216;
    _Float16* R = Q + 16777216;

    // ---- fused weight reorder (1 launch) ----
    WArgs wa;
    int cum = 0, si = 0;
    const _Float16* rp[23];
    auto addseg = [&](const float* src, int cin, int cout, int ck) {
        wa.seg[si].src = src; wa.seg[si].cin = cin; wa.seg[si].cout = cout;
        wa.seg[si].ck = ck; wa.seg[si].cum = cum;
        rp[si] = rwbase + cum;
        cum += cout * cin * 9; si++;
    };
    for (int i = 0; i < 5; ++i) addseg(w1 + (size_t)i * 9216, 32, 32, 32);
    addseg(wd2, 32, 64, 32);
    for (int i = 0; i < 4; ++i) addseg(w2 + (size_t)i * 36864, 64, 64, 64);
    addseg(wd3, 64, 128, 64);
    for (int i = 0; i < 4; ++i) addseg(w3 + (size_t)i * 147456, 128, 128, 64);
    addseg(wd4, 128, 256, 64);
    for (int i = 0; i < 4; ++i) addseg(w4 + (size_t)i * 589824, 256, 256, 64);
    for (int i = 0; i < 3; ++i) addseg(w5 + (size_t)i * 589824, 256, 256, 64);
    wa.total = cum;  // 5,299,200
    reorder_all<<<(cum + 255) / 256, 256, 0, stream>>>(wa, rwbase);

    // ---- zero-init sparse-written buffers + counters ----
    hipMemsetAsync(cnt, 0, 2 * sizeof(int), stream);
    hipMemsetAsync(Q, 0, 16777216 * sizeof(_Float16), stream);
    hipMemsetAsync(R, 0, 16777216 * sizeof(_Float16), stream);
    hipMemsetAsync(x1o, 0, 16777216 * sizeof(float), stream);

    // ---- masks + x0 + fused compaction ----
    {
        int n = B * 512 * 512;
        mask_make<<<(n + 255) / 256, 256, 0, stream>>>(x, mask_p, m1, P, act, cnt, B, 512 * 512);
        mask_down<<<(B * 256 * 256 + 255) / 256, 256, 0, stream>>>(m1, m2, B, 512, 512, 256, 256);
        mask_down<<<(B * 128 * 128 + 255) / 256, 256, 0, stream>>>(m2, m3, B, 256, 256, 128, 128);
        mask_down<<<(B * 64 * 64 + 255) / 256, 256, 0, stream>>>(m3, m4, B, 128, 128, 64, 64);
    }

    auto conv = [&](const _Float16* in, const _Float16* rwp, const float* sp, const float* tp,
                    const float* mk, const _Float16* rs, float* o32, _Float16* o16,
                    int Cin, int Cout, int Hin, int Win, int stride, int BM, int BN, int CK) {
        int Hout = Hin / stride, Wout = Win / stride, HWo = Hout * Wout;
        int TW = (Wout < BN) ? Wout : BN;
        int TH = BN / TW;
        dim3 grid(HWo / BN, Cout / BM, B);
        if (BM == 64 && BN == 128 && CK == 32)
            conv_mfma<64, 128, 32><<<grid, 256, 0, stream>>>(in, rwp, sp, tp, mk, rs, o32, o16,
                Cin, Cout, Hin, Win, Hout, Wout, TH, TW, stride, 1);
        else if (BM == 64 && BN == 128 && CK == 64)
            conv_mfma<64, 128, 64><<<grid, 256, 0, stream>>>(in, rwp, sp, tp, mk, rs, o32, o16,
                Cin, Cout, Hin, Win, Hout, Wout, TH, TW, stride, 1);
        else
            conv_mfma<128, 64, 64><<<grid, 256, 0, stream>>>(in, rwp, sp, tp, mk, rs, o32, o16,
                Cin, Cout, Hin, Win, Hout, Wout, TH, TW, stride, 1);
    };
    auto sconv = [&](const _Float16* in, const _Float16* rwp, const float* sp, const float* tp,
                     const _Float16* rs, float* o32, _Float16* o16) {
        // 128 sites per block (4 waves x 32); grid covers worst case, early-exit rest
        dim3 grid(2048, 1, B);
        conv_sparse<<<grid, 256, 0, stream>>>(in, rwp, sp, tp, act, cnt, rs, o32, o16, 512, 512, 1);
    };

    // ---- stage 1 (32ch, 512x512) sparse: P=x0 ----
    sconv(P, rp[0], s1 + 0,   t1 + 0,   nullptr, nullptr, Q);
    sconv(Q, rp[1], s1 + 32,  t1 + 32,  nullptr, nullptr, R);
    sconv(R, rp[2], s1 + 64,  t1 + 64,  Q,       nullptr, P);   // P inactive sites = 0 from x0
    sconv(P, rp[3], s1 + 96,  t1 + 96,  nullptr, nullptr, Q);
    sconv(Q, rp[4], s1 + 128, t1 + 128, P,       x1o,     R);   // x1 = R

    // ---- stage 2 (32->64, 512->256): in R ----
    conv(R, rp[5], s2 + 0,   t2 + 0,   m2, nullptr, nullptr, P, 32, 64, 512, 512, 2, 64, 128, 32);
    conv(P, rp[6], s2 + 64,  t2 + 64,  m2, nullptr, nullptr, Q, 64, 64, 256, 256, 1, 64, 128, 64);
    conv(Q, rp[7], s2 + 128, t2 + 128, m2, P,       nullptr, P, 64, 64, 256, 256, 1, 64, 128, 64);
    conv(P, rp[8], s2 + 192, t2 + 192, m2, nullptr, nullptr, Q, 64, 64, 256, 256, 1, 64, 128, 64);
    conv(Q, rp[9], s2 + 256, t2 + 256, m2, P,       x2o,     P, 64, 64, 256, 256, 1, 64, 128, 64);

    // ---- stage 3 (64->128, 256->128): x2 = P ----
    conv(P, rp[10], s3 + 0,   t3 + 0,   m3, nullptr, nullptr, Q, 64, 128, 256, 256, 2, 128, 64, 64);
    conv(Q, rp[11], s3 + 128, t3 + 128, m3, nullptr, nullptr, R, 128, 128, 128, 128, 1, 128, 64, 64);
    conv(R, rp[12], s3 + 256, t3 + 256, m3, Q,       nullptr, Q, 128, 128, 128, 128, 1, 128, 64, 64);
    conv(Q, rp[13], s3 + 384, t3 + 384, m3, nullptr, nullptr, R, 128, 128, 128, 128, 1, 128, 64, 64);
    conv(R, rp[14], s3 + 512, t3 + 512, m3, Q,       x3o,     Q, 128, 128, 128, 128, 1, 128, 64, 64);

    // ---- stage 4 (128->256, 128->64): x3 = Q ----
    conv(Q, rp[15], s4 + 0,    t4 + 0,    m4, nullptr, nullptr, P, 128, 256, 128, 128, 2, 128, 64, 64);
    conv(P, rp[16], s4 + 256,  t4 + 256,  m4, nullptr, nullptr, R, 256, 256, 64, 64, 1, 128, 64, 64);
    conv(R, rp[17], s4 + 512,  t4 + 512,  m4, P,       nullptr, P, 256, 256, 64, 64, 1, 128, 64, 64);
    conv(P, rp[18], s4 + 768,  t4 + 768,  m4, nullptr, nullptr, R, 256, 256, 64, 64, 1, 128, 64, 64);
    conv(R, rp[19], s4 + 1024, t4 + 1024, m4, P,       x4o,     P, 256, 256, 64, 64, 1, 128, 64, 64);

    // ---- conv5 (dense): x4 = P ----
    conv(P, rp[20], s5 + 0,   t5 + 0,   nullptr, nullptr, nullptr, Q, 256, 256, 64, 64, 2, 128, 64, 64);
    conv(Q, rp[21], s5 + 256, t5 + 256, nullptr, nullptr, nullptr, R, 256, 256, 32, 32, 1, 128, 64, 64);
    conv(R, rp[22], s5 + 512, t5 + 512, nullptr, nullptr, x5o, nullptr, 256, 256, 32, 32, 1, 128, 64, 64);
}

// Round 7
// 1087.049 us; speedup vs baseline: 2.0123x; 1.4330x over previous
//
#include <hip/hip_runtime.h>

typedef __attribute__((ext_vector_type(8))) _Float16 f16x8;
typedef __attribute__((ext_vector_type(4))) _Float16 f16x4;
typedef __attribute__((ext_vector_type(4))) float f32x4;

// ---------------------------------------------------------------------------
// mask_make: m = (mask_p < 0.1); x0 = fp16 blocked [b][pix][32] of x*mask;
// fused block-aggregated active-site compaction (1 global atomic / block).
// ---------------------------------------------------------------------------
__global__ void mask_make(const float* __restrict__ x, const float* __restrict__ mp,
                          float* __restrict__ m, _Float16* __restrict__ x0,
                          int* __restrict__ act, int* __restrict__ cnt,
                          int B, int HW) {
    int i = blockIdx.x * blockDim.x + threadIdx.x;
    const int tid = threadIdx.x;
    const int lane = tid & 63;
    const int wv = tid >> 6;
    bool active = (mp[i] < 0.1f);
    float mv = active ? 1.0f : 0.0f;
    m[i] = mv;
    int b = i / HW, p = i - b * HW;           // b uniform per block (HW % 256 == 0)
    const float* xb = x + ((size_t)b * 32) * HW + p;
    _Float16* ob = x0 + (size_t)i * 32;
    #pragma unroll
    for (int c = 0; c < 32; ++c) ob[c] = (_Float16)(xb[(size_t)c * HW] * mv);

    __shared__ int wcnt[4];
    __shared__ int bbase;
    unsigned long long ball = __ballot(active);
    int wtot = __popcll(ball);
    int prefix = __popcll(ball & ((1ull << lane) - 1ull));
    if (lane == 0) wcnt[wv] = wtot;
    __syncthreads();
    if (tid == 0) {
        int s = 0;
        #pragma unroll
        for (int w = 0; w < 4; ++w) { int tv = wcnt[w]; wcnt[w] = s; s += tv; }
        bbase = (s > 0) ? atomicAdd(&cnt[b], s) : 0;
    }
    __syncthreads();
    if (active) act[b * HW + bbase + wcnt[wv] + prefix] = p;
}

// 3x3 stride-2 pad-1 max-pool on (B,1,H,W) mask
__global__ void mask_down(const float* __restrict__ mi, float* __restrict__ mo,
                          int B, int Hi, int Wi, int Ho, int Wo) {
    int i = blockIdx.x * blockDim.x + threadIdx.x;
    if (i >= B * Ho * Wo) return;
    int wo = i % Wo;
    int t = i / Wo;
    int ho = t % Ho;
    int b = t / Ho;
    float v = 0.0f;
    #pragma unroll
    for (int kh = 0; kh < 3; ++kh) {
        int hi = ho * 2 + kh - 1;
        if (hi < 0 || hi >= Hi) continue;
        #pragma unroll
        for (int kw = 0; kw < 3; ++kw) {
            int wi = wo * 2 + kw - 1;
            if (wi < 0 || wi >= Wi) continue;
            v = fmaxf(v, mi[((size_t)b * Hi + hi) * Wi + wi]);
        }
    }
    mo[i] = v;
}

// ---------------------------------------------------------------------------
// Fused weight reorder: all 23 tensors, fp32 OIHW -> fp16 [chunk][co][CK]
// ---------------------------------------------------------------------------
struct WSeg { const float* src; int cin, cout, ck, cum; };
struct WArgs { WSeg seg[23]; int total; };

__global__ void reorder_all(WArgs A, _Float16* __restrict__ rw) {
    int idx = blockIdx.x * 256 + threadIdx.x;
    if (idx >= A.total) return;
    int s = 0;
    #pragma unroll
    for (int k = 1; k < 23; ++k) if (idx >= A.seg[k].cum) s = k;
    WSeg g = A.seg[s];
    int local = idx - g.cum;
    int kk = local % g.ck;
    int t2 = local / g.ck;
    int co = t2 % g.cout;
    int chunk = t2 / g.cout;
    int chunkc = g.cin / g.ck;
    int tap = chunk / chunkc, cc = chunk - tap * chunkc;
    int ci = cc * g.ck + kk;
    rw[g.cum + local] = (_Float16)g.src[((size_t)co * g.cin + ci) * 9 + tap];
}

// ---------------------------------------------------------------------------
// Dense implicit-GEMM conv3x3 (pad1, stride 1/2), fp16 MFMA, fp32 accum.
// BM=64, BN=64 pixels, K chunked by CK tap-major. Weight regs double-buffered
// (named awA/awB, 2-chunk unroll). Staging: 4 threads per pixel (coalesced).
// ---------------------------------------------------------------------------
template<int BM, int BN, int CK>
__global__ __launch_bounds__(256, 4)
void conv_mfma(const _Float16* __restrict__ in, const _Float16* __restrict__ rw,
               const float* __restrict__ s, const float* __restrict__ t,
               const float* __restrict__ mask, const _Float16* __restrict__ res,
               float* __restrict__ out32, _Float16* __restrict__ out16,
               int Cin, int Cout, int Hin, int Win, int Hout, int Wout,
               int TH, int TW, int stride, int relu)
{
    constexpr int WM = (BM >= 64) ? BM / 2 : BM;
    constexpr int WAVES_M = BM / WM;
    constexpr int WAVES_N = 4 / WAVES_M;
    constexpr int WN = BN / WAVES_N;
    constexpr int MR = WM / 16;
    constexpr int NR = WN / 16;
    constexpr int KH = CK / 32;
    constexpr int ELEMS = (CK * BN) / 256;   // halves per thread per chunk
    constexpr int NV = ELEMS / 8;
    constexpr int TPP = 256 / BN;            // threads per pixel
    constexpr int LDST = CK + 8;

    __shared__ _Float16 Bsm[2][BN * LDST];

    const int tid = threadIdx.x;
    const int lane = tid & 63;
    const int wv = tid >> 6;
    const int wm = wv / WAVES_N;
    const int wn = wv % WAVES_N;
    const int row = lane & 15, q = lane >> 4;

    const int tilesX = Wout / TW;
    const int oy0 = (blockIdx.x / tilesX) * TH;
    const int ox0 = (blockIdx.x % tilesX) * TW;
    const int co0 = blockIdx.y * BM;
    const int b = blockIdx.z;

    const int HWin = Hin * Win;
    const int HWo = Hout * Wout;
    const int cicn = Cin >> 5;
    const int cocn = Cout >> 5;
    const int chunkc = Cin / CK;
    const int nIter = 9 * chunkc;

    // staging: TPP threads cover one pixel's CK halves
    const int sn = tid / TPP;
    const int kb = (tid % TPP) * ELEMS;
    const int sty = sn / TW;
    const int stx = sn - sty * TW;
    const int soy = oy0 + sty;
    const int sox = ox0 + stx;

    f32x4 acc[MR][NR];
    #pragma unroll
    for (int m = 0; m < MR; ++m)
        #pragma unroll
        for (int n = 0; n < NR; ++n)
            #pragma unroll
            for (int r = 0; r < 4; ++r) acc[m][n][r] = 0.0f;

    auto LOADG = [&](int c, f16x8* dst) {
        int tap = c / chunkc, cc = c - tap * chunkc;
        int iy = soy * stride + (tap / 3) - 1;
        int ix = sox * stride + (tap - (tap / 3) * 3) - 1;
        bool ok = (iy >= 0 && iy < Hin && ix >= 0 && ix < Win);
        size_t pixoff = (size_t)iy * Win + ix;
        #pragma unroll
        for (int i = 0; i < NV; ++i) {
            int k = kb + 8 * i;
            const _Float16* p = in +
                (((size_t)(b * cicn + cc * KH + (k >> 5)) * HWin + pixoff) << 5) + (k & 31);
            dst[i] = ok ? *(const f16x8*)p : f16x8{};
        }
    };
    auto LOADW = [&](int c, f16x8 (&dst)[KH][MR]) {
        #pragma unroll
        for (int m = 0; m < MR; ++m) {
            int co = co0 + wm * WM + m * 16 + row;
            const _Float16* ap = rw + ((size_t)c * Cout + co) * CK + (q << 3);
            #pragma unroll
            for (int h = 0; h < KH; ++h) dst[h][m] = *(const f16x8*)(ap + 32 * h);
        }
    };
    auto WLDS = [&](int buf, const f16x8* v) {
        #pragma unroll
        for (int i = 0; i < NV; ++i)
            *(f16x8*)&Bsm[buf][sn * LDST + kb + 8 * i] = v[i];
    };
    auto DO_CHUNK = [&](const _Float16* bp, f16x8 (&awx)[KH][MR]) {
        f16x8 bh[KH][NR];
        #pragma unroll
        for (int n = 0; n < NR; ++n) {
            int nl = wn * WN + n * 16 + row;
            const _Float16* bb = bp + nl * LDST + (q << 3);
            #pragma unroll
            for (int h = 0; h < KH; ++h) bh[h][n] = *(const f16x8*)(bb + 32 * h);
        }
        #pragma unroll
        for (int h = 0; h < KH; ++h)
            #pragma unroll
            for (int m = 0; m < MR; ++m)
                #pragma unroll
                for (int n = 0; n < NR; ++n)
                    acc[m][n] = __builtin_amdgcn_mfma_f32_16x16x32_f16(awx[h][m], bh[h][n], acc[m][n], 0, 0, 0);
    };

    f16x8 awA[KH][MR], awB[KH][MR];
    f16x8 v[NV];
    LOADG(0, v);
    LOADW(0, awA);
    WLDS(0, v);
    __syncthreads();

    for (int c = 0; c < nIter; c += 2) {
        // even chunk c: Bsm[0], awA
        f16x8 v2[NV];
        bool h1 = (c + 1) < nIter;
        if (h1) { LOADG(c + 1, v2); LOADW(c + 1, awB); }
        DO_CHUNK(&Bsm[0][0], awA);
        if (h1) WLDS(1, v2);
        __syncthreads();
        if (!h1) break;
        // odd chunk c+1: Bsm[1], awB
        f16x8 v3[NV];
        bool h2 = (c + 2) < nIter;
        if (h2) { LOADG(c + 2, v3); LOADW(c + 2, awA); }
        DO_CHUNK(&Bsm[1][0], awB);
        if (h2) WLDS(0, v3);
        __syncthreads();
    }

    int pix[NR]; float mv[NR];
    #pragma unroll
    for (int n = 0; n < NR; ++n) {
        int nl = wn * WN + n * 16 + row;
        int ty = nl / TW, tx = nl - ty * TW;
        pix[n] = (oy0 + ty) * Wout + (ox0 + tx);
        mv[n] = mask ? mask[(size_t)b * HWo + pix[n]] : 1.0f;
    }
    #pragma unroll
    for (int m = 0; m < MR; ++m) {
        int cb = co0 + wm * WM + m * 16 + q * 4;
        float sc[4], sh[4];
        #pragma unroll
        for (int r = 0; r < 4; ++r) { sc[r] = s[cb + r]; sh[r] = t[cb + r]; }
        #pragma unroll
        for (int n = 0; n < NR; ++n) {
            size_t boff = ((size_t)(b * cocn + (cb >> 5)) * HWo + pix[n]) * 32 + (cb & 31);
            float val[4];
            #pragma unroll
            for (int r = 0; r < 4; ++r) val[r] = (acc[m][n][r] * sc[r] + sh[r]) * mv[n];
            if (res) {
                f16x4 rv = *(const f16x4*)&res[boff];
                #pragma unroll
                for (int r = 0; r < 4; ++r) val[r] += (float)rv[r];
            }
            if (relu) {
                #pragma unroll
                for (int r = 0; r < 4; ++r) val[r] = fmaxf(val[r], 0.0f);
            }
            if (out16) {
                f16x4 pk;
                #pragma unroll
                for (int r = 0; r < 4; ++r) pk[r] = (_Float16)val[r];
                *(f16x4*)&out16[boff] = pk;
            }
            if (out32) {
                #pragma unroll
                for (int r = 0; r < 4; ++r)
                    out32[((size_t)b * Cout + cb + r) * HWo + pix[n]] = val[r];
            }
        }
    }
}

// ---------------------------------------------------------------------------
// Sparse stage-1 conv, barrier-free: Cin=Cout=32 gathered over active list.
// 16 sites per wave (max wave count for latency hiding); lane (row,q)
// global-loads its MFMA B-fragment directly (16B of the 64B channel block).
// ---------------------------------------------------------------------------
__global__ __launch_bounds__(256, 4)
void conv_sparse(const _Float16* __restrict__ in, const _Float16* __restrict__ rw,
                 const float* __restrict__ s, const float* __restrict__ t,
                 const int* __restrict__ act, const int* __restrict__ cnt,
                 const _Float16* __restrict__ res,
                 float* __restrict__ out32, _Float16* __restrict__ out16,
                 int Hin, int Win, int relu)
{
    const int tid = threadIdx.x;
    const int lane = tid & 63;
    const int wv = tid >> 6;
    const int row = lane & 15, q = lane >> 4;
    const int b = blockIdx.z;
    const int HW = Hin * Win;
    const int nb = cnt[b];
    const int base = (blockIdx.x * 4 + wv) * 16;
    if (base >= nb) return;

    const int* actb = act + b * HW;
    const _Float16* inb = in + ((size_t)b * HW << 5);

    int j = base + row;
    bool vn = j < nb;
    int pn = vn ? actb[j] : 0;
    int py = pn / Win, px = pn - py * Win;

    f32x4 acc0, acc1;
    #pragma unroll
    for (int r = 0; r < 4; ++r) { acc0[r] = 0.0f; acc1[r] = 0.0f; }

    #pragma unroll
    for (int c = 0; c < 9; ++c) {
        const int dy = c / 3 - 1, dx = c - (c / 3) * 3 - 1;
        f16x8 a0 = *(const f16x8*)(rw + ((size_t)c * 32 + row) * 32 + (q << 3));
        f16x8 a1 = *(const f16x8*)(rw + ((size_t)c * 32 + 16 + row) * 32 + (q << 3));
        int iy = py + dy, ix = px + dx;
        bool ok = vn && iy >= 0 && iy < Hin && ix >= 0 && ix < Win;
        f16x8 bf = ok ? *(const f16x8*)(inb + ((size_t)(iy * Win + ix) << 5) + (q << 3))
                      : f16x8{};
        acc0 = __builtin_amdgcn_mfma_f32_16x16x32_f16(a0, bf, acc0, 0, 0, 0);
        acc1 = __builtin_amdgcn_mfma_f32_16x16x32_f16(a1, bf, acc1, 0, 0, 0);
    }

    if (!vn) return;
    size_t pbase = ((size_t)b * HW + pn) << 5;
    #pragma unroll
    for (int m = 0; m < 2; ++m) {
        const f32x4& am = m ? acc1 : acc0;
        int cb = m * 16 + q * 4;
        float val[4];
        #pragma unroll
        for (int r = 0; r < 4; ++r) val[r] = am[r] * s[cb + r] + t[cb + r];
        if (res) {
            f16x4 rv = *(const f16x4*)&res[pbase + cb];
            #pragma unroll
            for (int r = 0; r < 4; ++r) val[r] += (float)rv[r];
        }
        if (relu) {
            #pragma unroll
            for (int r = 0; r < 4; ++r) val[r] = fmaxf(val[r], 0.0f);
        }
        f16x4 pk;
        #pragma unroll
        for (int r = 0; r < 4; ++r) pk[r] = (_Float16)val[r];
        *(f16x4*)&out16[pbase + cb] = pk;
        if (out32) {
            #pragma unroll
            for (int r = 0; r < 4; ++r)
                out32[((size_t)(b * 32 + cb + r)) * HW + pn] = val[r];
        }
    }
}

extern "C" void kernel_launch(void* const* d_in, const int* in_sizes, int n_in,
                              void* d_out, int out_size, void* d_ws, size_t ws_size,
                              hipStream_t stream) {
    const int B = 2;

    const float* x      = (const float*)d_in[0];
    const float* mask_p = (const float*)d_in[1];
    const float* w1  = (const float*)d_in[2];
    const float* s1  = (const float*)d_in[3];
    const float* t1  = (const float*)d_in[4];
    const float* wd2 = (const float*)d_in[5];
    const float* w2  = (const float*)d_in[6];
    const float* s2  = (const float*)d_in[7];
    const float* t2  = (const float*)d_in[8];
    const float* wd3 = (const float*)d_in[9];
    const float* w3  = (const float*)d_in[10];
    const float* s3  = (const float*)d_in[11];
    const float* t3  = (const float*)d_in[12];
    const float* wd4 = (const float*)d_in[13];
    const float* w4  = (const float*)d_in[14];
    const float* s4  = (const float*)d_in[15];
    const float* t4  = (const float*)d_in[16];
    const float* w5  = (const float*)d_in[17];
    const float* s5  = (const float*)d_in[18];
    const float* t5  = (const float*)d_in[19];

    // d_out slices (fp32 NCHW)
    float* x1o = (float*)d_out;
    float* x2o = x1o + 16777216;
    float* x3o = x2o + 8388608;
    float* x4o = x3o + 4194304;
    float* x5o = x4o + 2097152;

    // workspace
    _Float16* rwbase = (_Float16*)d_ws;        // 5,299,200 halves
    float* m1 = (float*)d_ws + 2649600;
    float* m2 = m1 + 524288;
    float* m3 = m2 + 131072;
    float* m4 = m3 + 32768;
    int* act  = (int*)(m4 + 8192);             // 524288 ints
    int* cnt  = act + 524288;                  // 2 ints (+pad)
    _Float16* P = (_Float16*)(cnt + 32);
    _Float16* Q = P + 16777216;
    _Float16* R = Q + 16777216;

    // ---- fused weight reorder (1 launch) ----
    WArgs wa;
    int cum = 0, si = 0;
    const _Float16* rp[23];
    auto addseg = [&](const float* src, int cin, int cout, int ck) {
        wa.seg[si].src = src; wa.seg[si].cin = cin; wa.seg[si].cout = cout;
        wa.seg[si].ck = ck; wa.seg[si].cum = cum;
        rp[si] = rwbase + cum;
        cum += cout * cin * 9; si++;
    };
    for (int i = 0; i < 5; ++i) addseg(w1 + (size_t)i * 9216, 32, 32, 32);
    addseg(wd2, 32, 64, 32);
    for (int i = 0; i < 4; ++i) addseg(w2 + (size_t)i * 36864, 64, 64, 64);
    addseg(wd3, 64, 128, 64);
    for (int i = 0; i < 4; ++i) addseg(w3 + (size_t)i * 147456, 128, 128, 64);
    addseg(wd4, 128, 256, 64);
    for (int i = 0; i < 4; ++i) addseg(w4 + (size_t)i * 589824, 256, 256, 64);
    for (int i = 0; i < 3; ++i) addseg(w5 + (size_t)i * 589824, 256, 256, 64);
    wa.total = cum;  // 5,299,200
    reorder_all<<<(cum + 255) / 256, 256, 0, stream>>>(wa, rwbase);

    // ---- zero-init sparse-written buffers + counters ----
    hipMemsetAsync(cnt, 0, 2 * sizeof(int), stream);
    hipMemsetAsync(Q, 0, 16777216 * sizeof(_Float16), stream);
    hipMemsetAsync(R, 0, 16777216 * sizeof(_Float16), stream);
    hipMemsetAsync(x1o, 0, 16777216 * sizeof(float), stream);

    // ---- masks + x0 + fused compaction ----
    {
        int n = B * 512 * 512;
        mask_make<<<(n + 255) / 256, 256, 0, stream>>>(x, mask_p, m1, P, act, cnt, B, 512 * 512);
        mask_down<<<(B * 256 * 256 + 255) / 256, 256, 0, stream>>>(m1, m2, B, 512, 512, 256, 256);
        mask_down<<<(B * 128 * 128 + 255) / 256, 256, 0, stream>>>(m2, m3, B, 256, 256, 128, 128);
        mask_down<<<(B * 64 * 64 + 255) / 256, 256, 0, stream>>>(m3, m4, B, 128, 128, 64, 64);
    }

    auto conv = [&](const _Float16* in, const _Float16* rwp, const float* sp, const float* tp,
                    const float* mk, const _Float16* rs, float* o32, _Float16* o16,
                    int Cin, int Cout, int Hin, int Win, int stride, int CK) {
        int Hout = Hin / stride, Wout = Win / stride, HWo = Hout * Wout;
        int TW = (Wout < 64) ? Wout : 64;
        int TH = 64 / TW;
        dim3 grid(HWo / 64, Cout / 64, B);
        if (CK == 32)
            conv_mfma<64, 64, 32><<<grid, 256, 0, stream>>>(in, rwp, sp, tp, mk, rs, o32, o16,
                Cin, Cout, Hin, Win, Hout, Wout, TH, TW, stride, 1);
        else
            conv_mfma<64, 64, 64><<<grid, 256, 0, stream>>>(in, rwp, sp, tp, mk, rs, o32, o16,
                Cin, Cout, Hin, Win, Hout, Wout, TH, TW, stride, 1);
    };
    auto sconv = [&](const _Float16* in, const _Float16* rwp, const float* sp, const float* tp,
                     const _Float16* rs, float* o32, _Float16* o16) {
        // 64 sites per block (4 waves x 16); grid covers worst case, early-exit rest
        dim3 grid(1024, 1, B);
        conv_sparse<<<grid, 256, 0, stream>>>(in, rwp, sp, tp, act, cnt, rs, o32, o16, 512, 512, 1);
    };

    // ---- stage 1 (32ch, 512x512) sparse: P=x0 ----
    sconv(P, rp[0], s1 + 0,   t1 + 0,   nullptr, nullptr, Q);
    sconv(Q, rp[1], s1 + 32,  t1 + 32,  nullptr, nullptr, R);
    sconv(R, rp[2], s1 + 64,  t1 + 64,  Q,       nullptr, P);   // P inactive sites = 0 from x0
    sconv(P, rp[3], s1 + 96,  t1 + 96,  nullptr, nullptr, Q);
    sconv(Q, rp[4], s1 + 128, t1 + 128, P,       x1o,     R);   // x1 = R

    // ---- stage 2 (32->64, 512->256): in R ----
    conv(R, rp[5], s2 + 0,   t2 + 0,   m2, nullptr, nullptr, P, 32, 64, 512, 512, 2, 32);
    conv(P, rp[6], s2 + 64,  t2 + 64,  m2, nullptr, nullptr, Q, 64, 64, 256, 256, 1, 64);
    conv(Q, rp[7], s2 + 128, t2 + 128, m2, P,       nullptr, P, 64, 64, 256, 256, 1, 64);
    conv(P, rp[8], s2 + 192, t2 + 192, m2, nullptr, nullptr, Q, 64, 64, 256, 256, 1, 64);
    conv(Q, rp[9], s2 + 256, t2 + 256, m2, P,       x2o,     P, 64, 64, 256, 256, 1, 64);

    // ---- stage 3 (64->128, 256->128): x2 = P ----
    conv(P, rp[10], s3 + 0,   t3 + 0,   m3, nullptr, nullptr, Q, 64, 128, 256, 256, 2, 64);
    conv(Q, rp[11], s3 + 128, t3 + 128, m3, nullptr, nullptr, R, 128, 128, 128, 128, 1, 64);
    conv(R, rp[12], s3 + 256, t3 + 256, m3, Q,       nullptr, Q, 128, 128, 128, 128, 1, 64);
    conv(Q, rp[13], s3 + 384, t3 + 384, m3, nullptr, nullptr, R, 128, 128, 128, 128, 1, 64);
    conv(R, rp[14], s3 + 512, t3 + 512, m3, Q,       x3o,     Q, 128, 128, 128, 128, 1, 64);

    // ---- stage 4 (128->256, 128->64): x3 = Q ----
    conv(Q, rp[15], s4 + 0,    t4 + 0,    m4, nullptr, nullptr, P, 128, 256, 128, 128, 2, 64);
    conv(P, rp[16], s4 + 256,  t4 + 256,  m4, nullptr, nullptr, R, 256, 256, 64, 64, 1, 64);
    conv(R, rp[17], s4 + 512,  t4 + 512,  m4, P,       nullptr, P, 256, 256, 64, 64, 1, 64);
    conv(P, rp[18], s4 + 768,  t4 + 768,  m4, nullptr, nullptr, R, 256, 256, 64, 64, 1, 64);
    conv(R, rp[19], s4 + 1024, t4 + 1024, m4, P,       x4o,     P, 256, 256, 64, 64, 1, 64);

    // ---- conv5 (dense): x4 = P ----
    conv(P, rp[20], s5 + 0,   t5 + 0,   nullptr, nullptr, nullptr, Q, 256, 256, 64, 64, 2, 64);
    conv(Q, rp[21], s5 + 256, t5 + 256, nullptr, nullptr, nullptr, R, 256, 256, 32, 32, 1, 64);
    conv(R, rp[22], s5 + 512, t5 + 512, nullptr, nullptr, x5o, nullptr, 256, 256, 32, 32, 1, 64);
}